// Round 1
// baseline (590.555 us; speedup 1.0000x reference)
//
#include <hip/hip_runtime.h>
#include <math.h>

#define EPS 1e-5f

// ---------------- init: deg=1 (self loop), zero BN stats ----------------
__global__ void k_init(float* __restrict__ deg, float* __restrict__ stats, int N) {
    int i = blockIdx.x * blockDim.x + threadIdx.x;
    if (i < N) deg[i] = 1.0f;
    if (i < 256) stats[i] = 0.0f;
}

// ---------------- degree count over edges ----------------
__global__ void k_degree(const int* __restrict__ dst, float* __restrict__ deg, int E) {
    int i = blockIdx.x * blockDim.x + threadIdx.x;
    if (i < E) atomicAdd(&deg[dst[i]], 1.0f);
}

// ---------------- dinv = rsqrt(deg) in place ----------------
__global__ void k_rsqrt(float* __restrict__ deg, int N) {
    int i = blockIdx.x * blockDim.x + threadIdx.x;
    if (i < N) deg[i] = rsqrtf(deg[i]);
}

// ---------------- GEMM1: XW = x @ W1   (N x 128) @ (128 x 64) ----------------
__global__ __launch_bounds__(256) void k_gemm1(const float* __restrict__ x,
                                               const float* __restrict__ W1,
                                               float* __restrict__ XW, int N) {
    __shared__ float w[128 * 64];     // 32 KB
    __shared__ float xs[4][4][128];   // 8 KB: wave, row-in-batch, k
    for (int i = threadIdx.x; i < 128 * 64; i += 256) w[i] = W1[i];
    __syncthreads();
    int lane = threadIdx.x & 63;
    int wave = threadIdx.x >> 6;
    int gwave = blockIdx.x * 4 + wave;
    int nw = gridDim.x * 4;
    for (int r0 = gwave * 4; r0 < N; r0 += nw * 4) {
        int nr = min(4, N - r0);
        for (int j = 0; j < nr; ++j) {
            xs[wave][j][lane]      = x[(size_t)(r0 + j) * 128 + lane];
            xs[wave][j][64 + lane] = x[(size_t)(r0 + j) * 128 + 64 + lane];
        }
        float a0 = 0.f, a1 = 0.f, a2 = 0.f, a3 = 0.f;
#pragma unroll 8
        for (int k = 0; k < 128; ++k) {
            float wk = w[k * 64 + lane];
            a0 += xs[wave][0][k] * wk;
            a1 += xs[wave][1][k] * wk;
            a2 += xs[wave][2][k] * wk;
            a3 += xs[wave][3][k] * wk;
        }
        XW[(size_t)(r0 + 0) * 64 + lane] = a0;
        if (nr > 1) XW[(size_t)(r0 + 1) * 64 + lane] = a1;
        if (nr > 2) XW[(size_t)(r0 + 2) * 64 + lane] = a2;
        if (nr > 3) XW[(size_t)(r0 + 3) * 64 + lane] = a3;
    }
}

// ---------------- self-loop init: H[v] = XW[v] * dinv[v]^2 ----------------
__global__ void k_selfloop(const float* __restrict__ XW, const float* __restrict__ dinv,
                           float* __restrict__ H, int total) {
    int i = blockIdx.x * blockDim.x + threadIdx.x;
    if (i < total) {
        int v = i >> 6;
        float di = dinv[v];
        H[i] = XW[i] * di * di;
    }
}

// ---------------- edge scatter: one wave per edge, lane = feature ----------------
__global__ __launch_bounds__(256) void k_scatter(const int* __restrict__ src,
                                                 const int* __restrict__ dst,
                                                 const float* __restrict__ dinv,
                                                 const float* __restrict__ XW,
                                                 float* __restrict__ H, int E) {
    int wid = (blockIdx.x * blockDim.x + threadIdx.x) >> 6;
    int lane = threadIdx.x & 63;
    if (wid >= E) return;
    int s = src[wid];
    int d = dst[wid];
    float nrm = dinv[s] * dinv[d];
    float val = XW[(size_t)s * 64 + lane] * nrm;
    atomicAdd(&H[(size_t)d * 64 + lane], val);
}

// ---------------- BN stats: per-feature sum and sumsq ----------------
__global__ __launch_bounds__(256) void k_bnstats(const float* __restrict__ H,
                                                 float* __restrict__ stats, int N) {
    __shared__ float ssum[256], ssq[256];
    int f = threadIdx.x & 63;
    int sub = threadIdx.x >> 6;
    float s = 0.f, q = 0.f;
    for (int r = blockIdx.x * 4 + sub; r < N; r += gridDim.x * 4) {
        float v = H[(size_t)r * 64 + f];
        s += v;
        q += v * v;
    }
    ssum[threadIdx.x] = s;
    ssq[threadIdx.x] = q;
    __syncthreads();
    if (threadIdx.x < 64) {
        float ts = ssum[f] + ssum[64 + f] + ssum[128 + f] + ssum[192 + f];
        float tq = ssq[f] + ssq[64 + f] + ssq[128 + f] + ssq[192 + f];
        atomicAdd(&stats[f], ts);
        atomicAdd(&stats[64 + f], tq);
    }
}

// ---------------- GEMM2 with fused BN1+ReLU on the input ----------------
__global__ __launch_bounds__(256) void k_gemm2(const float* __restrict__ H1,
                                               const float* __restrict__ stats,
                                               const float* __restrict__ gamma,
                                               const float* __restrict__ beta,
                                               const float* __restrict__ W2,
                                               float* __restrict__ XW2, int N) {
    __shared__ float w[64 * 64];     // 16 KB
    __shared__ float xs[4][4][64];   // 4 KB
    for (int i = threadIdx.x; i < 64 * 64; i += 256) w[i] = W2[i];
    int lane = threadIdx.x & 63;
    int wave = threadIdx.x >> 6;
    float mean = stats[lane] / (float)N;
    float var = stats[64 + lane] / (float)N - mean * mean;
    float rstd = rsqrtf(var + EPS);
    float g = gamma[lane], bt = beta[lane];
    __syncthreads();
    int gwave = blockIdx.x * 4 + wave;
    int nw = gridDim.x * 4;
    for (int r0 = gwave * 4; r0 < N; r0 += nw * 4) {
        int nr = min(4, N - r0);
        for (int j = 0; j < nr; ++j) {
            float v = H1[(size_t)(r0 + j) * 64 + lane];
            v = (v - mean) * rstd * g + bt;
            xs[wave][j][lane] = fmaxf(v, 0.f);
        }
        float a0 = 0.f, a1 = 0.f, a2 = 0.f, a3 = 0.f;
#pragma unroll 8
        for (int k = 0; k < 64; ++k) {
            float wk = w[k * 64 + lane];
            a0 += xs[wave][0][k] * wk;
            a1 += xs[wave][1][k] * wk;
            a2 += xs[wave][2][k] * wk;
            a3 += xs[wave][3][k] * wk;
        }
        XW2[(size_t)(r0 + 0) * 64 + lane] = a0;
        if (nr > 1) XW2[(size_t)(r0 + 1) * 64 + lane] = a1;
        if (nr > 2) XW2[(size_t)(r0 + 2) * 64 + lane] = a2;
        if (nr > 3) XW2[(size_t)(r0 + 3) * 64 + lane] = a3;
    }
}

// ---------------- final BN (layer 2), in place on d_out ----------------
__global__ void k_bnfinal(float* __restrict__ out, const float* __restrict__ stats,
                          const float* __restrict__ gamma, const float* __restrict__ beta,
                          int N) {
    int i = blockIdx.x * blockDim.x + threadIdx.x;
    int total = N * 64;
    if (i < total) {
        int f = i & 63;
        float mean = stats[f] / (float)N;
        float var = stats[64 + f] / (float)N - mean * mean;
        float rstd = rsqrtf(var + EPS);
        out[i] = (out[i] - mean) * rstd * gamma[f] + beta[f];
    }
}

extern "C" void kernel_launch(void* const* d_in, const int* in_sizes, int n_in,
                              void* d_out, int out_size, void* d_ws, size_t ws_size,
                              hipStream_t stream) {
    const float* x      = (const float*)d_in[0];
    const int*   ei     = (const int*)d_in[1];     // int32 (jax x64 disabled)
    const float* W1     = (const float*)d_in[2];
    // b1 (d_in[3]) cancels under BN mean subtraction -> unused
    const float* gamma1 = (const float*)d_in[4];
    const float* beta1  = (const float*)d_in[5];
    const float* W2     = (const float*)d_in[6];
    // b2 (d_in[7]) cancels under BN -> unused
    const float* gamma2 = (const float*)d_in[8];
    const float* beta2  = (const float*)d_in[9];
    float* out = (float*)d_out;

    const int N = in_sizes[0] / 128;
    const int E = in_sizes[1] / 2;
    const int* src = ei;
    const int* dst = ei + E;

    char* ws = (char*)d_ws;
    float* dinv  = (float*)ws;                                  // N floats
    float* stats = (float*)(ws + 0x40000);                      // 256 floats: [L1 sum, L1 sq, L2 sum, L2 sq]
    float* XW    = (float*)(ws + 0x100000);                     // N*64 floats (reused for layer 2)
    float* H1    = (float*)(ws + 0x100000 + (size_t)N * 64 * 4); // N*64 floats

    const int total = N * 64;

    k_init<<<(N + 255) / 256, 256, 0, stream>>>(dinv, stats, N);
    k_degree<<<(E + 255) / 256, 256, 0, stream>>>(dst, dinv, E);
    k_rsqrt<<<(N + 255) / 256, 256, 0, stream>>>(dinv, N);

    // ---- layer 1 ----
    k_gemm1<<<1024, 256, 0, stream>>>(x, W1, XW, N);
    k_selfloop<<<(total + 255) / 256, 256, 0, stream>>>(XW, dinv, H1, total);
    k_scatter<<<(E + 3) / 4, 256, 0, stream>>>(src, dst, dinv, XW, H1, E);
    k_bnstats<<<256, 256, 0, stream>>>(H1, stats, N);

    // ---- layer 2 (BN1+ReLU fused into GEMM2 input) ----
    k_gemm2<<<512, 256, 0, stream>>>(H1, stats, gamma1, beta1, W2, XW, N);
    k_selfloop<<<(total + 255) / 256, 256, 0, stream>>>(XW, dinv, out, total);
    k_scatter<<<(E + 3) / 4, 256, 0, stream>>>(src, dst, dinv, XW, out, E);
    k_bnstats<<<256, 256, 0, stream>>>(out, stats + 128, N);
    k_bnfinal<<<(total + 255) / 256, 256, 0, stream>>>(out, stats + 128, gamma2, beta2, N);
}

// Round 2
// 381.815 us; speedup vs baseline: 1.5467x; 1.5467x over previous
//
#include <hip/hip_runtime.h>
#include <math.h>

#define EPS 1e-5f

// ---------------- zero cnt + stats ----------------
__global__ void k_zero(int* __restrict__ cnt, float* __restrict__ stats, int N) {
    int i = blockIdx.x * blockDim.x + threadIdx.x;
    if (i < N) cnt[i] = 0;
    if (i < 256) stats[i] = 0.0f;
}

// ---------------- in-degree histogram ----------------
__global__ void k_hist(const int* __restrict__ dst, int* __restrict__ cnt, int E) {
    int i = blockIdx.x * blockDim.x + threadIdx.x;
    if (i < E) atomicAdd(&cnt[dst[i]], 1);
}

// ---------------- per-block sums of cnt ----------------
__global__ void k_blocksum(const int* __restrict__ cnt, int* __restrict__ partial, int N) {
    __shared__ int s[256];
    int i = blockIdx.x * 256 + threadIdx.x;
    s[threadIdx.x] = (i < N) ? cnt[i] : 0;
    __syncthreads();
    for (int off = 128; off > 0; off >>= 1) {
        if (threadIdx.x < off) s[threadIdx.x] += s[threadIdx.x + off];
        __syncthreads();
    }
    if (threadIdx.x == 0) partial[blockIdx.x] = s[0];
}

// ---------------- exclusive scan of partials (B <= 256), write rowptr[N] ----------------
__global__ void k_scanpartial(int* __restrict__ partial, int B, int* __restrict__ rowptr, int N) {
    __shared__ int s[256];
    int t = threadIdx.x;
    int v = (t < B) ? partial[t] : 0;
    s[t] = v;
    __syncthreads();
    for (int off = 1; off < 256; off <<= 1) {
        int add = (t >= off) ? s[t - off] : 0;
        __syncthreads();
        s[t] += add;
        __syncthreads();
    }
    if (t < B) partial[t] = s[t] - v;      // exclusive
    if (t == 255) rowptr[N] = s[255];      // total = E
}

// ---------------- expand: rowptr / cursor / dinv ----------------
__global__ void k_expand(const int* __restrict__ cnt, const int* __restrict__ partial,
                         int* __restrict__ rowptr, int* __restrict__ cursor,
                         float* __restrict__ dinv, int N) {
    __shared__ int s[256];
    int t = threadIdx.x;
    int i = blockIdx.x * 256 + t;
    int c = (i < N) ? cnt[i] : 0;
    s[t] = c;
    __syncthreads();
    for (int off = 1; off < 256; off <<= 1) {
        int add = (t >= off) ? s[t - off] : 0;
        __syncthreads();
        s[t] += add;
        __syncthreads();
    }
    if (i < N) {
        int excl = s[t] - c + partial[blockIdx.x];
        rowptr[i] = excl;
        cursor[i] = excl;
        dinv[i] = rsqrtf((float)(c + 1));   // +1 self loop
    }
}

// ---------------- fill CSR src lists ----------------
__global__ void k_fill(const int* __restrict__ src, const int* __restrict__ dst,
                       int* __restrict__ cursor, int* __restrict__ csr_src, int E) {
    int e = blockIdx.x * blockDim.x + threadIdx.x;
    if (e < E) {
        int d = dst[e];
        int pos = atomicAdd(&cursor[d], 1);
        csr_src[pos] = src[e];
    }
}

// ---------------- GEMM1: Y = (x @ W1) * dinv[row]   (N x 128)@(128 x 64) ----------------
__global__ __launch_bounds__(256) void k_gemm1(const float* __restrict__ x,
                                               const float* __restrict__ W1,
                                               const float* __restrict__ dinv,
                                               float* __restrict__ Y, int N) {
    __shared__ float w[128 * 64];
    __shared__ float xs[4][4][128];
    for (int i = threadIdx.x; i < 128 * 64; i += 256) w[i] = W1[i];
    __syncthreads();
    int lane = threadIdx.x & 63;
    int wave = threadIdx.x >> 6;
    int gwave = blockIdx.x * 4 + wave;
    int nw = gridDim.x * 4;
    for (int r0 = gwave * 4; r0 < N; r0 += nw * 4) {
        int nr = min(4, N - r0);
        for (int j = 0; j < nr; ++j) {
            xs[wave][j][lane]      = x[(size_t)(r0 + j) * 128 + lane];
            xs[wave][j][64 + lane] = x[(size_t)(r0 + j) * 128 + 64 + lane];
        }
        float a0 = 0.f, a1 = 0.f, a2 = 0.f, a3 = 0.f;
#pragma unroll 8
        for (int k = 0; k < 128; ++k) {
            float wk = w[k * 64 + lane];
            a0 += xs[wave][0][k] * wk;
            a1 += xs[wave][1][k] * wk;
            a2 += xs[wave][2][k] * wk;
            a3 += xs[wave][3][k] * wk;
        }
        Y[(size_t)(r0 + 0) * 64 + lane] = a0 * dinv[r0];
        if (nr > 1) Y[(size_t)(r0 + 1) * 64 + lane] = a1 * dinv[r0 + 1];
        if (nr > 2) Y[(size_t)(r0 + 2) * 64 + lane] = a2 * dinv[r0 + 2];
        if (nr > 3) Y[(size_t)(r0 + 3) * 64 + lane] = a3 * dinv[r0 + 3];
    }
}

// ---------------- aggregate (gather) + BN stats ----------------
// H[v] = dinv[v] * (Y[v] + sum_{e in CSR[v]} Y[src[e]])
__global__ __launch_bounds__(256) void k_agg(const float* __restrict__ Y,
                                             const int* __restrict__ rowptr,
                                             const int* __restrict__ csr,
                                             const float* __restrict__ dinv,
                                             float* __restrict__ H,
                                             float* __restrict__ stats, int N) {
    __shared__ float ssum[4][64], ssq[4][64];
    int lane = threadIdx.x & 63;
    int wave = threadIdx.x >> 6;
    float s = 0.f, q = 0.f;
    int gw = blockIdx.x * 4 + wave;
    int nw = gridDim.x * 4;
    for (int v = gw; v < N; v += nw) {
        int r0 = rowptr[v], r1 = rowptr[v + 1];
        float acc = Y[(size_t)v * 64 + lane];
        int e = r0;
        for (; e + 3 < r1; e += 4) {
            int s0 = csr[e], s1 = csr[e + 1], s2 = csr[e + 2], s3 = csr[e + 3];
            float y0 = Y[(size_t)s0 * 64 + lane];
            float y1 = Y[(size_t)s1 * 64 + lane];
            float y2 = Y[(size_t)s2 * 64 + lane];
            float y3 = Y[(size_t)s3 * 64 + lane];
            acc += y0 + y1 + y2 + y3;
        }
        for (; e < r1; ++e) acc += Y[(size_t)csr[e] * 64 + lane];
        float h = acc * dinv[v];
        H[(size_t)v * 64 + lane] = h;
        s += h;
        q += h * h;
    }
    ssum[wave][lane] = s;
    ssq[wave][lane] = q;
    __syncthreads();
    if (threadIdx.x < 64) {
        atomicAdd(&stats[lane],      ssum[0][lane] + ssum[1][lane] + ssum[2][lane] + ssum[3][lane]);
        atomicAdd(&stats[64 + lane], ssq[0][lane] + ssq[1][lane] + ssq[2][lane] + ssq[3][lane]);
    }
}

// ---------------- GEMM2 with fused BN1+ReLU input, *dinv output ----------------
__global__ __launch_bounds__(256) void k_gemm2(const float* __restrict__ H1,
                                               const float* __restrict__ stats,
                                               const float* __restrict__ gamma,
                                               const float* __restrict__ beta,
                                               const float* __restrict__ W2,
                                               const float* __restrict__ dinv,
                                               float* __restrict__ Y2, int N) {
    __shared__ float w[64 * 64];
    __shared__ float xs[4][4][64];
    for (int i = threadIdx.x; i < 64 * 64; i += 256) w[i] = W2[i];
    int lane = threadIdx.x & 63;
    int wave = threadIdx.x >> 6;
    float mean = stats[lane] / (float)N;
    float var = stats[64 + lane] / (float)N - mean * mean;
    float rstd = rsqrtf(var + EPS);
    float g = gamma[lane], bt = beta[lane];
    __syncthreads();
    int gwave = blockIdx.x * 4 + wave;
    int nw = gridDim.x * 4;
    for (int r0 = gwave * 4; r0 < N; r0 += nw * 4) {
        int nr = min(4, N - r0);
        for (int j = 0; j < nr; ++j) {
            float v = H1[(size_t)(r0 + j) * 64 + lane];
            v = (v - mean) * rstd * g + bt;
            xs[wave][j][lane] = fmaxf(v, 0.f);
        }
        float a0 = 0.f, a1 = 0.f, a2 = 0.f, a3 = 0.f;
#pragma unroll 8
        for (int k = 0; k < 64; ++k) {
            float wk = w[k * 64 + lane];
            a0 += xs[wave][0][k] * wk;
            a1 += xs[wave][1][k] * wk;
            a2 += xs[wave][2][k] * wk;
            a3 += xs[wave][3][k] * wk;
        }
        Y2[(size_t)(r0 + 0) * 64 + lane] = a0 * dinv[r0];
        if (nr > 1) Y2[(size_t)(r0 + 1) * 64 + lane] = a1 * dinv[r0 + 1];
        if (nr > 2) Y2[(size_t)(r0 + 2) * 64 + lane] = a2 * dinv[r0 + 2];
        if (nr > 3) Y2[(size_t)(r0 + 3) * 64 + lane] = a3 * dinv[r0 + 3];
    }
}

// ---------------- final BN (layer 2), in place on d_out ----------------
__global__ void k_bnfinal(float* __restrict__ out, const float* __restrict__ stats,
                          const float* __restrict__ gamma, const float* __restrict__ beta,
                          int N) {
    int i = blockIdx.x * blockDim.x + threadIdx.x;
    int total = N * 64;
    if (i < total) {
        int f = i & 63;
        float mean = stats[f] / (float)N;
        float var = stats[64 + f] / (float)N - mean * mean;
        float rstd = rsqrtf(var + EPS);
        out[i] = (out[i] - mean) * rstd * gamma[f] + beta[f];
    }
}

extern "C" void kernel_launch(void* const* d_in, const int* in_sizes, int n_in,
                              void* d_out, int out_size, void* d_ws, size_t ws_size,
                              hipStream_t stream) {
    const float* x      = (const float*)d_in[0];
    const int*   ei     = (const int*)d_in[1];
    const float* W1     = (const float*)d_in[2];
    // b1 (d_in[3]) cancels under BN mean subtraction -> unused
    const float* gamma1 = (const float*)d_in[4];
    const float* beta1  = (const float*)d_in[5];
    const float* W2     = (const float*)d_in[6];
    // b2 (d_in[7]) cancels under BN -> unused
    const float* gamma2 = (const float*)d_in[8];
    const float* beta2  = (const float*)d_in[9];
    float* out = (float*)d_out;

    const int N = in_sizes[0] / 128;
    const int E = in_sizes[1] / 2;
    const int* src = ei;
    const int* dst = ei + E;

    const size_t NB = (size_t)N * 64 * 4;   // bytes of one [N,64] fp32 buffer
    char* ws = (char*)d_ws;
    float* dinv    = (float*)ws;                       // N floats
    float* stats   = (float*)(ws + 0x40000);           // 256 floats: [L1 sum, L1 sq, L2 sum, L2 sq]
    int*   partial = (int*)  (ws + 0x41000);           // 256 ints
    int*   rowptr  = (int*)  (ws + 0x42000);           // N+1 ints
    int*   cursor  = (int*)  (ws + 0x80000);           // N ints
    int*   cnt     = (int*)  (ws + 0xC0000);           // N ints
    float* Y       = (float*)(ws + 0x100000);          // N*64 floats (reused for layer 2)
    float* H1      = (float*)(ws + 0x100000 + NB);     // N*64 floats
    int*   csr_src = (int*)  (ws + 0x100000 + 2 * NB); // E ints

    const int B = (N + 255) / 256;          // 196 for N=50000 (must be <= 256)
    const int total = N * 64;

    // ---- CSR build + norm ----
    k_zero<<<B, 256, 0, stream>>>(cnt, stats, N);
    k_hist<<<(E + 255) / 256, 256, 0, stream>>>(dst, cnt, E);
    k_blocksum<<<B, 256, 0, stream>>>(cnt, partial, N);
    k_scanpartial<<<1, 256, 0, stream>>>(partial, B, rowptr, N);
    k_expand<<<B, 256, 0, stream>>>(cnt, partial, rowptr, cursor, dinv, N);
    k_fill<<<(E + 255) / 256, 256, 0, stream>>>(src, dst, cursor, csr_src, E);

    // ---- layer 1 ----
    k_gemm1<<<1024, 256, 0, stream>>>(x, W1, dinv, Y, N);
    k_agg<<<1024, 256, 0, stream>>>(Y, rowptr, csr_src, dinv, H1, stats, N);

    // ---- layer 2 ----
    k_gemm2<<<512, 256, 0, stream>>>(H1, stats, gamma1, beta1, W2, dinv, Y, N);
    k_agg<<<1024, 256, 0, stream>>>(Y, rowptr, csr_src, dinv, out, stats + 128, N);
    k_bnfinal<<<(total + 255) / 256, 256, 0, stream>>>(out, stats + 128, gamma2, beta2, N);
}

// Round 3
// 363.544 us; speedup vs baseline: 1.6244x; 1.0503x over previous
//
#include <hip/hip_runtime.h>
#include <hip/hip_fp16.h>
#include <math.h>

#define EPS 1e-5f

// ---------------- zero cnt + stats ----------------
__global__ void k_zero(int* __restrict__ cnt, float* __restrict__ stats, int N) {
    int i = blockIdx.x * blockDim.x + threadIdx.x;
    if (i < N) cnt[i] = 0;
    if (i < 256) stats[i] = 0.0f;
}

// ---------------- in-degree histogram ----------------
__global__ void k_hist(const int* __restrict__ dst, int* __restrict__ cnt, int E) {
    int i = blockIdx.x * blockDim.x + threadIdx.x;
    if (i < E) atomicAdd(&cnt[dst[i]], 1);
}

// ---------------- per-block sums of cnt ----------------
__global__ void k_blocksum(const int* __restrict__ cnt, int* __restrict__ partial, int N) {
    __shared__ int s[256];
    int i = blockIdx.x * 256 + threadIdx.x;
    s[threadIdx.x] = (i < N) ? cnt[i] : 0;
    __syncthreads();
    for (int off = 128; off > 0; off >>= 1) {
        if (threadIdx.x < off) s[threadIdx.x] += s[threadIdx.x + off];
        __syncthreads();
    }
    if (threadIdx.x == 0) partial[blockIdx.x] = s[0];
}

// ---------------- exclusive scan of partials (B <= 256), write rowptr[N] ----------------
__global__ void k_scanpartial(int* __restrict__ partial, int B, int* __restrict__ rowptr, int N) {
    __shared__ int s[256];
    int t = threadIdx.x;
    int v = (t < B) ? partial[t] : 0;
    s[t] = v;
    __syncthreads();
    for (int off = 1; off < 256; off <<= 1) {
        int add = (t >= off) ? s[t - off] : 0;
        __syncthreads();
        s[t] += add;
        __syncthreads();
    }
    if (t < B) partial[t] = s[t] - v;      // exclusive
    if (t == 255) rowptr[N] = s[255];      // total = E
}

// ---------------- expand: rowptr / cursor / dinv ----------------
__global__ void k_expand(const int* __restrict__ cnt, const int* __restrict__ partial,
                         int* __restrict__ rowptr, int* __restrict__ cursor,
                         float* __restrict__ dinv, int N) {
    __shared__ int s[256];
    int t = threadIdx.x;
    int i = blockIdx.x * 256 + t;
    int c = (i < N) ? cnt[i] : 0;
    s[t] = c;
    __syncthreads();
    for (int off = 1; off < 256; off <<= 1) {
        int add = (t >= off) ? s[t - off] : 0;
        __syncthreads();
        s[t] += add;
        __syncthreads();
    }
    if (i < N) {
        int excl = s[t] - c + partial[blockIdx.x];
        rowptr[i] = excl;
        cursor[i] = excl;
        dinv[i] = rsqrtf((float)(c + 1));   // +1 self loop
    }
}

// ---------------- fill CSR src lists ----------------
__global__ void k_fill(const int* __restrict__ src, const int* __restrict__ dst,
                       int* __restrict__ cursor, int* __restrict__ csr_src, int E) {
    int e = blockIdx.x * blockDim.x + threadIdx.x;
    if (e < E) {
        int d = dst[e];
        int pos = atomicAdd(&cursor[d], 1);
        csr_src[pos] = src[e];
    }
}

// ---------------- GEMM1: Y = fp16((x @ W1) * dinv[row])   (N x 128)@(128 x 64) ----------------
__global__ __launch_bounds__(256) void k_gemm1(const float* __restrict__ x,
                                               const float* __restrict__ W1,
                                               const float* __restrict__ dinv,
                                               __half* __restrict__ Y, int N) {
    __shared__ float w[128 * 64];
    __shared__ float xs[4][4][128];
    for (int i = threadIdx.x; i < 128 * 64; i += 256) w[i] = W1[i];
    __syncthreads();
    int lane = threadIdx.x & 63;
    int wave = threadIdx.x >> 6;
    int gwave = blockIdx.x * 4 + wave;
    int nw = gridDim.x * 4;
    for (int r0 = gwave * 4; r0 < N; r0 += nw * 4) {
        int nr = min(4, N - r0);
        for (int j = 0; j < nr; ++j) {
            xs[wave][j][lane]      = x[(size_t)(r0 + j) * 128 + lane];
            xs[wave][j][64 + lane] = x[(size_t)(r0 + j) * 128 + 64 + lane];
        }
        float a0 = 0.f, a1 = 0.f, a2 = 0.f, a3 = 0.f;
#pragma unroll 8
        for (int k = 0; k < 128; ++k) {
            float wk = w[k * 64 + lane];
            a0 += xs[wave][0][k] * wk;
            a1 += xs[wave][1][k] * wk;
            a2 += xs[wave][2][k] * wk;
            a3 += xs[wave][3][k] * wk;
        }
        Y[(size_t)(r0 + 0) * 64 + lane] = __float2half(a0 * dinv[r0]);
        if (nr > 1) Y[(size_t)(r0 + 1) * 64 + lane] = __float2half(a1 * dinv[r0 + 1]);
        if (nr > 2) Y[(size_t)(r0 + 2) * 64 + lane] = __float2half(a2 * dinv[r0 + 2]);
        if (nr > 3) Y[(size_t)(r0 + 3) * 64 + lane] = __float2half(a3 * dinv[r0 + 3]);
    }
}

// ---------------- aggregate (gather, fp16 payload) + BN stats ----------------
// Half-wave per node: lane = (node-half, feature-pair). H[v] = dinv[v]*(Y[v]+sum Y[src])
__global__ __launch_bounds__(256) void k_agg(const __half2* __restrict__ Yh,
                                             const int* __restrict__ rowptr,
                                             const int* __restrict__ csr,
                                             const float* __restrict__ dinv,
                                             float2* __restrict__ H,
                                             float* __restrict__ stats, int N) {
    __shared__ float ssum[8][64], ssq[8][64];
    int lane = threadIdx.x & 63;
    int wave = threadIdx.x >> 6;
    int hf = lane >> 5;
    int l = lane & 31;
    int hw = wave * 2 + hf;            // half-wave id in block, 0..7
    float s0 = 0.f, s1 = 0.f, q0 = 0.f, q1 = 0.f;
    int ghw = blockIdx.x * 8 + hw;
    int nhw = gridDim.x * 8;
    for (int v = ghw; v < N; v += nhw) {
        int r0 = rowptr[v], r1 = rowptr[v + 1];
        float2 f = __half22float2(Yh[(size_t)v * 32 + l]);
        float a0 = f.x, a1 = f.y;
        int e = r0;
        for (; e + 3 < r1; e += 4) {
            int i0 = csr[e], i1 = csr[e + 1], i2 = csr[e + 2], i3 = csr[e + 3];
            float2 f0 = __half22float2(Yh[(size_t)i0 * 32 + l]);
            float2 f1 = __half22float2(Yh[(size_t)i1 * 32 + l]);
            float2 f2 = __half22float2(Yh[(size_t)i2 * 32 + l]);
            float2 f3 = __half22float2(Yh[(size_t)i3 * 32 + l]);
            a0 += f0.x + f1.x + f2.x + f3.x;
            a1 += f0.y + f1.y + f2.y + f3.y;
        }
        for (; e < r1; ++e) {
            float2 fe = __half22float2(Yh[(size_t)csr[e] * 32 + l]);
            a0 += fe.x; a1 += fe.y;
        }
        float di = dinv[v];
        a0 *= di; a1 *= di;
        H[(size_t)v * 32 + l] = make_float2(a0, a1);
        s0 += a0; s1 += a1; q0 += a0 * a0; q1 += a1 * a1;
    }
    ssum[hw][2 * l] = s0; ssum[hw][2 * l + 1] = s1;
    ssq[hw][2 * l] = q0;  ssq[hw][2 * l + 1] = q1;
    __syncthreads();
    if (threadIdx.x < 64) {
        float ts = 0.f, tq = 0.f;
#pragma unroll
        for (int i = 0; i < 8; ++i) { ts += ssum[i][threadIdx.x]; tq += ssq[i][threadIdx.x]; }
        atomicAdd(&stats[threadIdx.x], ts);
        atomicAdd(&stats[64 + threadIdx.x], tq);
    }
}

// ---------------- GEMM2 with fused BN1+ReLU input, fp16 *dinv output ----------------
__global__ __launch_bounds__(256) void k_gemm2(const float* __restrict__ H1,
                                               const float* __restrict__ stats,
                                               const float* __restrict__ gamma,
                                               const float* __restrict__ beta,
                                               const float* __restrict__ W2,
                                               const float* __restrict__ dinv,
                                               __half* __restrict__ Y2, int N) {
    __shared__ float w[64 * 64];
    __shared__ float xs[4][4][64];
    for (int i = threadIdx.x; i < 64 * 64; i += 256) w[i] = W2[i];
    int lane = threadIdx.x & 63;
    int wave = threadIdx.x >> 6;
    float mean = stats[lane] / (float)N;
    float var = stats[64 + lane] / (float)N - mean * mean;
    float rstd = rsqrtf(var + EPS);
    float g = gamma[lane], bt = beta[lane];
    __syncthreads();
    int gwave = blockIdx.x * 4 + wave;
    int nw = gridDim.x * 4;
    for (int r0 = gwave * 4; r0 < N; r0 += nw * 4) {
        int nr = min(4, N - r0);
        for (int j = 0; j < nr; ++j) {
            float v = H1[(size_t)(r0 + j) * 64 + lane];
            v = (v - mean) * rstd * g + bt;
            xs[wave][j][lane] = fmaxf(v, 0.f);
        }
        float a0 = 0.f, a1 = 0.f, a2 = 0.f, a3 = 0.f;
#pragma unroll 8
        for (int k = 0; k < 64; ++k) {
            float wk = w[k * 64 + lane];
            a0 += xs[wave][0][k] * wk;
            a1 += xs[wave][1][k] * wk;
            a2 += xs[wave][2][k] * wk;
            a3 += xs[wave][3][k] * wk;
        }
        Y2[(size_t)(r0 + 0) * 64 + lane] = __float2half(a0 * dinv[r0]);
        if (nr > 1) Y2[(size_t)(r0 + 1) * 64 + lane] = __float2half(a1 * dinv[r0 + 1]);
        if (nr > 2) Y2[(size_t)(r0 + 2) * 64 + lane] = __float2half(a2 * dinv[r0 + 2]);
        if (nr > 3) Y2[(size_t)(r0 + 3) * 64 + lane] = __float2half(a3 * dinv[r0 + 3]);
    }
}

// ---------------- final BN (layer 2), in place on d_out ----------------
__global__ void k_bnfinal(float* __restrict__ out, const float* __restrict__ stats,
                          const float* __restrict__ gamma, const float* __restrict__ beta,
                          int N) {
    int i = blockIdx.x * blockDim.x + threadIdx.x;
    int total = N * 64;
    if (i < total) {
        int f = i & 63;
        float mean = stats[f] / (float)N;
        float var = stats[64 + f] / (float)N - mean * mean;
        float rstd = rsqrtf(var + EPS);
        out[i] = (out[i] - mean) * rstd * gamma[f] + beta[f];
    }
}

extern "C" void kernel_launch(void* const* d_in, const int* in_sizes, int n_in,
                              void* d_out, int out_size, void* d_ws, size_t ws_size,
                              hipStream_t stream) {
    const float* x      = (const float*)d_in[0];
    const int*   ei     = (const int*)d_in[1];
    const float* W1     = (const float*)d_in[2];
    // b1 (d_in[3]) cancels under BN mean subtraction -> unused
    const float* gamma1 = (const float*)d_in[4];
    const float* beta1  = (const float*)d_in[5];
    const float* W2     = (const float*)d_in[6];
    // b2 (d_in[7]) cancels under BN -> unused
    const float* gamma2 = (const float*)d_in[8];
    const float* beta2  = (const float*)d_in[9];
    float* out = (float*)d_out;

    const int N = in_sizes[0] / 128;
    const int E = in_sizes[1] / 2;
    const int* src = ei;
    const int* dst = ei + E;

    const size_t NB = (size_t)N * 64 * 4;   // bytes of one [N,64] fp32 buffer
    char* ws = (char*)d_ws;
    float* dinv    = (float*)ws;                       // N floats
    float* stats   = (float*)(ws + 0x40000);           // 256 floats: [L1 sum, L1 sq, L2 sum, L2 sq]
    int*   partial = (int*)  (ws + 0x41000);           // 256 ints
    int*   rowptr  = (int*)  (ws + 0x42000);           // N+1 ints
    int*   cursor  = (int*)  (ws + 0x80000);           // N ints
    int*   cnt     = (int*)  (ws + 0xC0000);           // N ints
    __half* Y      = (__half*)(ws + 0x100000);         // N*64 halfs (reused for layer 2)
    float* H1      = (float*)(ws + 0x100000 + NB);     // N*64 floats
    int*   csr_src = (int*)  (ws + 0x100000 + 2 * NB); // E ints

    const int B = (N + 255) / 256;          // 196 for N=50000 (must be <= 256)
    const int total = N * 64;

    // ---- CSR build + norm ----
    k_zero<<<B, 256, 0, stream>>>(cnt, stats, N);
    k_hist<<<(E + 255) / 256, 256, 0, stream>>>(dst, cnt, E);
    k_blocksum<<<B, 256, 0, stream>>>(cnt, partial, N);
    k_scanpartial<<<1, 256, 0, stream>>>(partial, B, rowptr, N);
    k_expand<<<B, 256, 0, stream>>>(cnt, partial, rowptr, cursor, dinv, N);
    k_fill<<<(E + 255) / 256, 256, 0, stream>>>(src, dst, cursor, csr_src, E);

    // ---- layer 1 ----
    k_gemm1<<<1024, 256, 0, stream>>>(x, W1, dinv, Y, N);
    k_agg<<<2048, 256, 0, stream>>>((const __half2*)Y, rowptr, csr_src, dinv,
                                    (float2*)H1, stats, N);

    // ---- layer 2 ----
    k_gemm2<<<1024, 256, 0, stream>>>(H1, stats, gamma1, beta1, W2, dinv, Y, N);
    k_agg<<<2048, 256, 0, stream>>>((const __half2*)Y, rowptr, csr_src, dinv,
                                    (float2*)out, stats + 128, N);
    k_bnfinal<<<(total + 255) / 256, 256, 0, stream>>>(out, stats + 128, gamma2, beta2, N);
}

// Round 4
// 330.061 us; speedup vs baseline: 1.7892x; 1.1014x over previous
//
#include <hip/hip_runtime.h>
#include <hip/hip_fp16.h>
#include <math.h>

#define EPS 1e-5f

// ---------------- zero cnt + stats ----------------
__global__ void k_zero(int* __restrict__ cnt, float* __restrict__ stats, int N) {
    int i = blockIdx.x * blockDim.x + threadIdx.x;
    if (i < N) cnt[i] = 0;
    if (i < 256) stats[i] = 0.0f;
}

// ---------------- in-degree histogram ----------------
__global__ void k_hist(const int* __restrict__ dst, int* __restrict__ cnt, int E) {
    int i = blockIdx.x * blockDim.x + threadIdx.x;
    if (i < E) atomicAdd(&cnt[dst[i]], 1);
}

// ---------------- per-block sums of PADDED counts ----------------
__global__ void k_blocksum(const int* __restrict__ cnt, int* __restrict__ partial, int N) {
    __shared__ int s[256];
    int i = blockIdx.x * 256 + threadIdx.x;
    int c = (i < N) ? cnt[i] : 0;
    s[threadIdx.x] = (c + 3) & ~3;      // pad to multiple of 4
    __syncthreads();
    for (int off = 128; off > 0; off >>= 1) {
        if (threadIdx.x < off) s[threadIdx.x] += s[threadIdx.x + off];
        __syncthreads();
    }
    if (threadIdx.x == 0) partial[blockIdx.x] = s[0];
}

// ---------------- exclusive scan of partials (B <= 256), write rowptr[N] ----------------
__global__ void k_scanpartial(int* __restrict__ partial, int B, int* __restrict__ rowptr, int N) {
    __shared__ int s[256];
    int t = threadIdx.x;
    int v = (t < B) ? partial[t] : 0;
    s[t] = v;
    __syncthreads();
    for (int off = 1; off < 256; off <<= 1) {
        int add = (t >= off) ? s[t - off] : 0;
        __syncthreads();
        s[t] += add;
        __syncthreads();
    }
    if (t < B) partial[t] = s[t] - v;      // exclusive
    if (t == 255) rowptr[N] = s[255];      // total padded size
}

// ---------------- expand: rowptr/cursor/dinv + csr pad slots + zero Y row N ----------------
__global__ void k_expand(const int* __restrict__ cnt, const int* __restrict__ partial,
                         int* __restrict__ rowptr, int* __restrict__ cursor,
                         float* __restrict__ dinv, int* __restrict__ csr,
                         __half2* __restrict__ Yh, int N) {
    __shared__ int s[256];
    int t = threadIdx.x;
    int i = blockIdx.x * 256 + t;
    int c = (i < N) ? cnt[i] : 0;
    int cp = (c + 3) & ~3;
    s[t] = cp;
    __syncthreads();
    for (int off = 1; off < 256; off <<= 1) {
        int add = (t >= off) ? s[t - off] : 0;
        __syncthreads();
        s[t] += add;
        __syncthreads();
    }
    if (i < N) {
        int excl = s[t] - cp + partial[blockIdx.x];
        rowptr[i] = excl;
        cursor[i] = excl;
        dinv[i] = rsqrtf((float)(c + 1));   // +1 self loop
        for (int p = excl + c; p < excl + cp; ++p) csr[p] = N;   // pad -> zero row
    }
    if (blockIdx.x == 0 && t < 32) Yh[(size_t)N * 32 + t] = __half2half2(__float2half(0.f));
}

// ---------------- FUSED: gemm1 (blocks < G) || CSR fill (blocks >= G) ----------------
// gemm: Y = fp16((x @ W1) * dinv[row]); fill: csr[cursor[dst]++] = src
__global__ __launch_bounds__(256) void k_gemm1_fill(const float* __restrict__ x,
                                                    const float* __restrict__ W1,
                                                    const float* __restrict__ dinv,
                                                    __half* __restrict__ Y, int N,
                                                    const int* __restrict__ src,
                                                    const int* __restrict__ dst,
                                                    int* __restrict__ cursor,
                                                    int* __restrict__ csr, int E, int G) {
    if ((int)blockIdx.x >= G) {
        int t = (blockIdx.x - G) * 256 + threadIdx.x;
        int stride = (gridDim.x - G) * 256;
        for (int e = t; e < E; e += stride) {
            int d = dst[e];
            int pos = atomicAdd(&cursor[d], 1);
            csr[pos] = src[e];
        }
        return;
    }
    __shared__ float w[128 * 64];
    __shared__ float xs[4][4][128];
    for (int i = threadIdx.x; i < 128 * 64; i += 256) w[i] = W1[i];
    __syncthreads();
    int lane = threadIdx.x & 63;
    int wave = threadIdx.x >> 6;
    int gwave = blockIdx.x * 4 + wave;
    int nw = G * 4;
    for (int r0 = gwave * 4; r0 < N; r0 += nw * 4) {
        int nr = min(4, N - r0);
        for (int j = 0; j < nr; ++j) {
            xs[wave][j][lane]      = x[(size_t)(r0 + j) * 128 + lane];
            xs[wave][j][64 + lane] = x[(size_t)(r0 + j) * 128 + 64 + lane];
        }
        float a0 = 0.f, a1 = 0.f, a2 = 0.f, a3 = 0.f;
#pragma unroll 8
        for (int k = 0; k < 128; ++k) {
            float wk = w[k * 64 + lane];
            a0 += xs[wave][0][k] * wk;
            a1 += xs[wave][1][k] * wk;
            a2 += xs[wave][2][k] * wk;
            a3 += xs[wave][3][k] * wk;
        }
        Y[(size_t)(r0 + 0) * 64 + lane] = __float2half(a0 * dinv[r0]);
        if (nr > 1) Y[(size_t)(r0 + 1) * 64 + lane] = __float2half(a1 * dinv[r0 + 1]);
        if (nr > 2) Y[(size_t)(r0 + 2) * 64 + lane] = __float2half(a2 * dinv[r0 + 2]);
        if (nr > 3) Y[(size_t)(r0 + 3) * 64 + lane] = __float2half(a3 * dinv[r0 + 3]);
    }
}

// ---------------- aggregate: 2 adjacent nodes per half-wave, padded 4-edge batches ----------------
__global__ __launch_bounds__(256) void k_agg(const __half2* __restrict__ Yh,
                                             const int* __restrict__ rowptr,
                                             const int* __restrict__ csr,
                                             const float* __restrict__ dinv,
                                             float2* __restrict__ H,
                                             float* __restrict__ stats, int N) {
    __shared__ float ssum[8][64], ssq[8][64];
    int lane = threadIdx.x & 63;
    int wave = threadIdx.x >> 6;
    int l = lane & 31;
    int hw = wave * 2 + (lane >> 5);
    int chain = blockIdx.x * 8 + hw;
    int nch = gridDim.x * 8;
    float sx = 0.f, sy = 0.f, qx = 0.f, qy = 0.f;
    for (int v0 = 2 * chain; v0 < N; v0 += 2 * nch) {
        int v1 = v0 + 1;
        bool h1 = v1 < N;
        int r00 = rowptr[v0], r01 = rowptr[v0 + 1];
        int r11 = h1 ? rowptr[v0 + 2] : r01;
        float2 a0 = __half22float2(Yh[(size_t)v0 * 32 + l]);
        float2 a1 = __half22float2(Yh[(size_t)min(v1, N) * 32 + l]);
        float x0 = a0.x, y0 = a0.y, x1 = a1.x, y1 = a1.y;
        int n0 = (r01 - r00) >> 2, n1 = (r11 - r01) >> 2;
        int nc = min(n0, n1);
        int e0 = r00, e1 = r01;
        for (int t = 0; t < nc; ++t) {
            int i0 = csr[e0], i1 = csr[e0 + 1], i2 = csr[e0 + 2], i3 = csr[e0 + 3];
            int j0 = csr[e1], j1 = csr[e1 + 1], j2 = csr[e1 + 2], j3 = csr[e1 + 3];
            e0 += 4; e1 += 4;
            float2 f0 = __half22float2(Yh[(size_t)i0 * 32 + l]);
            float2 f1 = __half22float2(Yh[(size_t)i1 * 32 + l]);
            float2 f2 = __half22float2(Yh[(size_t)i2 * 32 + l]);
            float2 f3 = __half22float2(Yh[(size_t)i3 * 32 + l]);
            float2 g0 = __half22float2(Yh[(size_t)j0 * 32 + l]);
            float2 g1 = __half22float2(Yh[(size_t)j1 * 32 + l]);
            float2 g2 = __half22float2(Yh[(size_t)j2 * 32 + l]);
            float2 g3 = __half22float2(Yh[(size_t)j3 * 32 + l]);
            x0 += f0.x + f1.x + f2.x + f3.x;
            y0 += f0.y + f1.y + f2.y + f3.y;
            x1 += g0.x + g1.x + g2.x + g3.x;
            y1 += g0.y + g1.y + g2.y + g3.y;
        }
        for (int t = nc; t < n0; ++t) {
            int i0 = csr[e0], i1 = csr[e0 + 1], i2 = csr[e0 + 2], i3 = csr[e0 + 3];
            e0 += 4;
            float2 f0 = __half22float2(Yh[(size_t)i0 * 32 + l]);
            float2 f1 = __half22float2(Yh[(size_t)i1 * 32 + l]);
            float2 f2 = __half22float2(Yh[(size_t)i2 * 32 + l]);
            float2 f3 = __half22float2(Yh[(size_t)i3 * 32 + l]);
            x0 += f0.x + f1.x + f2.x + f3.x;
            y0 += f0.y + f1.y + f2.y + f3.y;
        }
        for (int t = nc; t < n1; ++t) {
            int j0 = csr[e1], j1 = csr[e1 + 1], j2 = csr[e1 + 2], j3 = csr[e1 + 3];
            e1 += 4;
            float2 g0 = __half22float2(Yh[(size_t)j0 * 32 + l]);
            float2 g1 = __half22float2(Yh[(size_t)j1 * 32 + l]);
            float2 g2 = __half22float2(Yh[(size_t)j2 * 32 + l]);
            float2 g3 = __half22float2(Yh[(size_t)j3 * 32 + l]);
            x1 += g0.x + g1.x + g2.x + g3.x;
            y1 += g0.y + g1.y + g2.y + g3.y;
        }
        float d0 = dinv[v0];
        float d1 = dinv[min(v1, N - 1)];
        x0 *= d0; y0 *= d0;
        x1 *= d1; y1 *= d1;
        H[(size_t)v0 * 32 + l] = make_float2(x0, y0);
        if (h1) H[(size_t)v1 * 32 + l] = make_float2(x1, y1);
        else { x1 = 0.f; y1 = 0.f; }
        sx += x0 + x1; sy += y0 + y1;
        qx += x0 * x0 + x1 * x1; qy += y0 * y0 + y1 * y1;
    }
    ssum[hw][2 * l] = sx; ssum[hw][2 * l + 1] = sy;
    ssq[hw][2 * l] = qx;  ssq[hw][2 * l + 1] = qy;
    __syncthreads();
    if (threadIdx.x < 64) {
        float ts = 0.f, tq = 0.f;
#pragma unroll
        for (int i = 0; i < 8; ++i) { ts += ssum[i][threadIdx.x]; tq += ssq[i][threadIdx.x]; }
        atomicAdd(&stats[threadIdx.x], ts);
        atomicAdd(&stats[64 + threadIdx.x], tq);
    }
}

// ---------------- GEMM2 with fused BN1+ReLU input, fp16 *dinv output ----------------
__global__ __launch_bounds__(256) void k_gemm2(const float* __restrict__ H1,
                                               const float* __restrict__ stats,
                                               const float* __restrict__ gamma,
                                               const float* __restrict__ beta,
                                               const float* __restrict__ W2,
                                               const float* __restrict__ dinv,
                                               __half* __restrict__ Y2, int N) {
    __shared__ float w[64 * 64];
    __shared__ float xs[4][4][64];
    for (int i = threadIdx.x; i < 64 * 64; i += 256) w[i] = W2[i];
    int lane = threadIdx.x & 63;
    int wave = threadIdx.x >> 6;
    float mean = stats[lane] / (float)N;
    float var = stats[64 + lane] / (float)N - mean * mean;
    float rstd = rsqrtf(var + EPS);
    float g = gamma[lane], bt = beta[lane];
    __syncthreads();
    int gwave = blockIdx.x * 4 + wave;
    int nw = gridDim.x * 4;
    for (int r0 = gwave * 4; r0 < N; r0 += nw * 4) {
        int nr = min(4, N - r0);
        for (int j = 0; j < nr; ++j) {
            float v = H1[(size_t)(r0 + j) * 64 + lane];
            v = (v - mean) * rstd * g + bt;
            xs[wave][j][lane] = fmaxf(v, 0.f);
        }
        float a0 = 0.f, a1 = 0.f, a2 = 0.f, a3 = 0.f;
#pragma unroll 8
        for (int k = 0; k < 64; ++k) {
            float wk = w[k * 64 + lane];
            a0 += xs[wave][0][k] * wk;
            a1 += xs[wave][1][k] * wk;
            a2 += xs[wave][2][k] * wk;
            a3 += xs[wave][3][k] * wk;
        }
        Y2[(size_t)(r0 + 0) * 64 + lane] = __float2half(a0 * dinv[r0]);
        if (nr > 1) Y2[(size_t)(r0 + 1) * 64 + lane] = __float2half(a1 * dinv[r0 + 1]);
        if (nr > 2) Y2[(size_t)(r0 + 2) * 64 + lane] = __float2half(a2 * dinv[r0 + 2]);
        if (nr > 3) Y2[(size_t)(r0 + 3) * 64 + lane] = __float2half(a3 * dinv[r0 + 3]);
    }
}

// ---------------- final BN (layer 2), in place on d_out ----------------
__global__ void k_bnfinal(float* __restrict__ out, const float* __restrict__ stats,
                          const float* __restrict__ gamma, const float* __restrict__ beta,
                          int N) {
    int i = blockIdx.x * blockDim.x + threadIdx.x;
    int total = N * 64;
    if (i < total) {
        int f = i & 63;
        float mean = stats[f] / (float)N;
        float var = stats[64 + f] / (float)N - mean * mean;
        float rstd = rsqrtf(var + EPS);
        out[i] = (out[i] - mean) * rstd * gamma[f] + beta[f];
    }
}

extern "C" void kernel_launch(void* const* d_in, const int* in_sizes, int n_in,
                              void* d_out, int out_size, void* d_ws, size_t ws_size,
                              hipStream_t stream) {
    const float* x      = (const float*)d_in[0];
    const int*   ei     = (const int*)d_in[1];
    const float* W1     = (const float*)d_in[2];
    // b1 (d_in[3]) cancels under BN mean subtraction -> unused
    const float* gamma1 = (const float*)d_in[4];
    const float* beta1  = (const float*)d_in[5];
    const float* W2     = (const float*)d_in[6];
    // b2 (d_in[7]) cancels under BN -> unused
    const float* gamma2 = (const float*)d_in[8];
    const float* beta2  = (const float*)d_in[9];
    float* out = (float*)d_out;

    const int N = in_sizes[0] / 128;
    const int E = in_sizes[1] / 2;
    const int* src = ei;
    const int* dst = ei + E;

    char* ws = (char*)d_ws;
    float* dinv    = (float*)ws;                       // N floats
    float* stats   = (float*)(ws + 0x40000);           // 256 floats
    int*   partial = (int*)  (ws + 0x41000);           // 256 ints
    int*   rowptr  = (int*)  (ws + 0x42000);           // N+1 ints
    int*   cursor  = (int*)  (ws + 0x80000);           // N ints
    int*   cnt     = (int*)  (ws + 0xC0000);           // N ints
    __half* Y      = (__half*)(ws + 0x100000);         // (N+1)*64 halfs (row N = zeros)
    size_t ybytes  = ((size_t)(N + 1) * 64 * 2 + 4095) & ~(size_t)4095;
    float* H1      = (float*)(ws + 0x100000 + ybytes); // N*64 floats
    int*   csr     = (int*)  (ws + 0x100000 + ybytes + (size_t)N * 256); // E+3N+pad ints

    const int B = (N + 255) / 256;          // 196 for N=50000 (must be <= 256)
    const int total = N * 64;
    const int G = 768, F = 256;             // fused kernel split

    // ---- CSR build (padded to x4, pads -> zero row N) ----
    k_zero<<<B, 256, 0, stream>>>(cnt, stats, N);
    k_hist<<<(E + 255) / 256, 256, 0, stream>>>(dst, cnt, E);
    k_blocksum<<<B, 256, 0, stream>>>(cnt, partial, N);
    k_scanpartial<<<1, 256, 0, stream>>>(partial, B, rowptr, N);
    k_expand<<<B, 256, 0, stream>>>(cnt, partial, rowptr, cursor, dinv, csr, (__half2*)Y, N);

    // ---- layer 1: gemm1 || fill (concurrent in one dispatch) ----
    k_gemm1_fill<<<G + F, 256, 0, stream>>>(x, W1, dinv, Y, N, src, dst, cursor, csr, E, G);
    k_agg<<<2048, 256, 0, stream>>>((const __half2*)Y, rowptr, csr, dinv,
                                    (float2*)H1, stats, N);

    // ---- layer 2 ----
    k_gemm2<<<1024, 256, 0, stream>>>(H1, stats, gamma1, beta1, W2, dinv, Y, N);
    k_agg<<<2048, 256, 0, stream>>>((const __half2*)Y, rowptr, csr, dinv,
                                    (float2*)out, stats + 128, N);
    k_bnfinal<<<(total + 255) / 256, 256, 0, stream>>>(out, stats + 128, gamma2, beta2, N);
}